// Round 13
// baseline (154.681 us; speedup 1.0000x reference)
//
#include <hip/hip_runtime.h>

#define WIDTH 128
#define SLOPE 0.01f
#define SBS 512
#define FBM 16

typedef __attribute__((ext_vector_type(8))) short short8;
typedef __attribute__((ext_vector_type(4))) float f32x4;

__device__ __forceinline__ unsigned short f2bf(float f) {
    unsigned b = __float_as_uint(f);
    b += 0x7FFFu + ((b >> 16) & 1u);   // round-to-nearest-even
    return (unsigned short)(b >> 16);
}
__device__ __forceinline__ float4 upk(uint2 u) {   // 4 bf16 -> 4 f32 (exact)
    float4 r;
    r.x = __uint_as_float(u.x << 16);
    r.y = __uint_as_float(u.x & 0xFFFF0000u);
    r.z = __uint_as_float(u.y << 16);
    r.w = __uint_as_float(u.y & 0xFFFF0000u);
    return r;
}
// monotone bf16(u16) <-> u16 map: unsigned compare == float compare
__device__ __forceinline__ unsigned short map16(unsigned short x) {
    return (x & 0x8000u) ? (unsigned short)(~x) : (unsigned short)(x | 0x8000u);
}
__device__ __forceinline__ unsigned short unmap16(unsigned u) {
    return (unsigned short)((u & 0x8000u) ? (u ^ 0x8000u) : (~u & 0xFFFFu));
}
// packed unsigned-16 min (2 mapped bf16 per dword), VOP3P
__device__ __forceinline__ unsigned pkmin(unsigned a, unsigned b) {
    unsigned r;
    asm("v_pk_min_u16 %0, %1, %2" : "=v"(r) : "v"(a), "v"(b));
    return r;
}
// XOR-swizzled LDS byte offset for row-major [16][512B] A tile (T2/G4)
__device__ __forceinline__ int swz(int lr, int bc) {
    return lr * 512 + (bc ^ ((lr & 7) << 4));
}

// ------- prep: xsb = map16(bf16(x_src)) | hist+rank | W fold+transpose -----
__global__ void prep_kernel(const float* __restrict__ x_src,
                            const float* __restrict__ W,
                            const int* __restrict__ e,
                            unsigned short* __restrict__ xsb,
                            unsigned short* __restrict__ Wt,
                            unsigned* __restrict__ counts,
                            int* __restrict__ rank,
                            int NS, int E, int nconv, int nhist) {
    int b = blockIdx.x;
    if (b < nconv) {
        int i = b * 256 + threadIdx.x;          // float4 units over x_src
        if (i < NS * 32) {
            float4 v = reinterpret_cast<const float4*>(x_src)[i];
            ushort4 o;
            o.x = map16(f2bf(v.x)); o.y = map16(f2bf(v.y));
            o.z = map16(f2bf(v.z)); o.w = map16(f2bf(v.w));
            *reinterpret_cast<ushort4*>(xsb + (size_t)i * 4) = o;
        }
    } else if (b < nconv + nhist) {
        int i = (b - nconv) * 256 + threadIdx.x;
        if (i < E) {
            int dst = e[E + i];
            rank[i] = (int)atomicAdd(&counts[dst], 1u);
        }
    } else {
        int t = (b - nconv - nhist) * 256 + threadIdx.x;
        if (t < 128 * 64) {
            int n = t & 127, kc = t >> 7;       // k = kc*4+j over 0..255
            ushort4 o;
            unsigned short* op = &o.x;
            #pragma unroll
            for (int j = 0; j < 4; ++j) {
                int k = kc * 4 + j;
                float v;
                if (k < 128) v = W[(size_t)k * 128 + n] + W[(size_t)(k + 128) * 128 + n];
                else         v = -W[(size_t)k * 128 + n];
                op[j] = f2bf(v);
            }
            *reinterpret_cast<ushort4*>(Wt + (size_t)n * 256 + kc * 4) = o;
        }
    }
}

// ---------------- scan + scatter (counting sort by dst) --------------------
__global__ void block_sum_kernel(const unsigned* __restrict__ counts,
                                 unsigned* __restrict__ bsums, int M) {
    int i = blockIdx.x * SBS + threadIdx.x;
    unsigned v = (i < M) ? counts[i] : 0u;
    for (int d = 32; d > 0; d >>= 1) v += __shfl_down(v, d);
    __shared__ unsigned ws[SBS / 64];
    int lane = threadIdx.x & 63, w = threadIdx.x >> 6;
    if (lane == 0) ws[w] = v;
    __syncthreads();
    if (threadIdx.x == 0) {
        unsigned s = 0;
        for (int k = 0; k < SBS / 64; ++k) s += ws[k];
        bsums[blockIdx.x] = s;
    }
}

__global__ void bsum_scan_kernel(const unsigned* __restrict__ bsums,
                                 unsigned* __restrict__ bbase, int NB,
                                 int* __restrict__ offsets, int M) {
    __shared__ unsigned s[256];
    int t = threadIdx.x;
    unsigned v = (t < NB) ? bsums[t] : 0u;
    s[t] = v;
    __syncthreads();
    for (int off = 1; off < 256; off <<= 1) {
        unsigned n = (t >= off) ? s[t - off] : 0u;
        __syncthreads();
        s[t] += n;
        __syncthreads();
    }
    if (t < NB) bbase[t] = s[t] - v;
    if (t == 255) offsets[M] = (int)s[255];
}

__global__ void scan_final_kernel(const unsigned* __restrict__ counts,
                                  const unsigned* __restrict__ bbase,
                                  int* __restrict__ offsets, int M) {
    int b = blockIdx.x, t = threadIdx.x;
    int i = b * SBS + t;
    unsigned c = (i < M) ? counts[i] : 0u;
    unsigned v = c;
    int lane = t & 63, w = t >> 6;
    for (int d = 1; d < 64; d <<= 1) {
        unsigned n = __shfl_up(v, d);
        if (lane >= d) v += n;
    }
    __shared__ unsigned ws[SBS / 64];
    if (lane == 63) ws[w] = v;
    __syncthreads();
    unsigned wbase = 0;
    for (int k = 0; k < w; ++k) wbase += ws[k];
    if (i < M) offsets[i] = (int)(bbase[b] + wbase + v - c);
}

__global__ void scatter_kernel(const int* __restrict__ e,
                               const int* __restrict__ offsets,
                               const int* __restrict__ rank,
                               int* __restrict__ csr, int E) {
    int i = blockIdx.x * blockDim.x + threadIdx.x;
    if (i < E) {
        int dst = e[E + i];
        csr[offsets[dst] + rank[i]] = e[i];
    }
}

// ---------------- Fused: scalar-index gather-min + MFMA GEMM ---------------
// Block = 16 rows, 4 waves; ONE WAVE PER ROW (4 rows sequential in pairs).
// Indices flow entirely through SGPRs (readfirstlane -> s_load), so each
// gather is  global_load_dword v, lane*4, s[base]  -- zero VGPR addresses,
// zero LDS in the address chain -> 32 loads in flight per wave.
// A = [bf16(x_dst) | mn] in XOR-swizzled LDS; h^T = W't*A^T; out = xb+lrelu.
// M % FBM == 0.
template<int XSB>
__global__ __launch_bounds__(256, 4) void fused_kernel(
        const float* __restrict__ x_src,
        const unsigned short* __restrict__ xsb,
        const float* __restrict__ x_dst,
        const int* __restrict__ offsets,
        const int* __restrict__ csr,
        const unsigned short* __restrict__ Wt,
        const float* __restrict__ bias,
        float* __restrict__ out, int M, int E) {
    __shared__ __align__(16) unsigned short At[FBM * 256];  // 8 KB
    char* Ab = reinterpret_cast<char*>(At);
    int tid = threadIdx.x;
    int lane = tid & 63;
    int blockRow = blockIdx.x * FBM;

    // ---- stage xb tile: 16 rows x 128 cols bf16, coalesced ----
    #pragma unroll
    for (int i = 0; i < FBM * 32 / 256; ++i) {   // 2 float4 per thread
        int u = tid + 256 * i;
        int lr = u >> 5, c4 = u & 31;
        float4 v = reinterpret_cast<const float4*>(x_dst)[(size_t)(blockRow + lr) * 32 + c4];
        ushort4 o;
        o.x = f2bf(v.x); o.y = f2bf(v.y); o.z = f2bf(v.z); o.w = f2bf(v.w);
        *reinterpret_cast<ushort4*>(Ab + swz(lr, c4 * 8)) = o;
    }

    // ---- gather-min: wave-per-row, scalar index chain ----
    int wvu = __builtin_amdgcn_readfirstlane(tid >> 6);
    int rbase = blockRow + wvu * 4;
    int off[5];
    #pragma unroll
    for (int k = 0; k < 5; ++k)
        off[k] = __builtin_amdgcn_readfirstlane(offsets[rbase + k]);
    int Elast = E - 1;
    const unsigned* xs = reinterpret_cast<const unsigned*>(xsb);

    unsigned outw[4];        // final (col 2*lane, 2*lane+1) pair per row
    #pragma unroll
    for (int pr = 0; pr < 2; ++pr) {             // two row-pairs
        unsigned va[16], vb[16];
        int begA = off[pr * 2 + 0], endA = off[pr * 2 + 1];
        int begB = off[pr * 2 + 1], endB = off[pr * 2 + 2];
        int degA = endA - begA, degB = endB - begB;
        int limA = min(max(endA - 1, begA), Elast);
        int limB = min(max(endB - 1, begB), Elast);
        if (XSB) {
            // 32 independent dword gathers, scalar bases
            #pragma unroll
            for (int j = 0; j < 16; ++j) {
                int pA = min(begA + j, limA);
                int iA = __builtin_amdgcn_readfirstlane(csr[pA]);
                va[j] = xs[(size_t)(unsigned)iA * 64u + lane];
                int pB = min(begB + j, limB);
                int iB = __builtin_amdgcn_readfirstlane(csr[pB]);
                vb[j] = xs[(size_t)(unsigned)iB * 64u + lane];
            }
            #pragma unroll
            for (int s = 8; s >= 1; s >>= 1)
                #pragma unroll
                for (int j = 0; j < s; ++j) {
                    va[j] = pkmin(va[j], va[j + s]);
                    vb[j] = pkmin(vb[j], vb[j + s]);
                }
            unsigned mnA = va[0], mnB = vb[0];
            // rare tails (deg > 16), scalar-bounded loops
            for (int e0 = 16; e0 < degA; ++e0) {
                int idx = __builtin_amdgcn_readfirstlane(csr[begA + e0]);
                mnA = pkmin(mnA, xs[(size_t)(unsigned)idx * 64u + lane]);
            }
            for (int e0 = 16; e0 < degB; ++e0) {
                int idx = __builtin_amdgcn_readfirstlane(csr[begB + e0]);
                mnB = pkmin(mnB, xs[(size_t)(unsigned)idx * 64u + lane]);
            }
            outw[pr * 2 + 0] = (unsigned)unmap16(mnA & 0xFFFFu)
                             | ((unsigned)unmap16(mnA >> 16) << 16);
            outw[pr * 2 + 1] = (unsigned)unmap16(mnB & 0xFFFFu)
                             | ((unsigned)unmap16(mnB >> 16) << 16);
        } else {
            // fallback (ws too small; never hit): f32 serial gather
            const float2* xf = reinterpret_cast<const float2*>(x_src);
            float2 mA = make_float2(INFINITY, INFINITY);
            float2 mB = mA;
            for (int e0 = 0; e0 < degA; ++e0) {
                int idx = __builtin_amdgcn_readfirstlane(csr[begA + e0]);
                float2 v = xf[(size_t)idx * 64 + lane];
                mA.x = fminf(mA.x, v.x); mA.y = fminf(mA.y, v.y);
            }
            for (int e0 = 0; e0 < degB; ++e0) {
                int idx = __builtin_amdgcn_readfirstlane(csr[begB + e0]);
                float2 v = xf[(size_t)idx * 64 + lane];
                mB.x = fminf(mB.x, v.x); mB.y = fminf(mB.y, v.y);
            }
            outw[pr * 2 + 0] = (unsigned)f2bf(mA.x) | ((unsigned)f2bf(mA.y) << 16);
            outw[pr * 2 + 1] = (unsigned)f2bf(mB.x) | ((unsigned)f2bf(mB.y) << 16);
        }
    }

    // ---- write mn halves (lane owns cols 2*lane, 2*lane+1 of each row) ----
    #pragma unroll
    for (int r = 0; r < 4; ++r) {
        int lr = wvu * 4 + r;
        int deg = off[r + 1] - off[r];
        unsigned o = outw[r];
        if (deg == 0)   // empty row: mn := xb  =>  h = xb@W0 exactly
            o = *reinterpret_cast<const unsigned*>(Ab + swz(lr, lane * 4));
        *reinterpret_cast<unsigned*>(Ab + swz(lr, 256 + lane * 4)) = o;
    }
    __syncthreads();

    // ---- MFMA GEMM: A (16x256) from LDS, B (folded W') from L2 ----
    int l15 = lane & 15;
    int q = lane >> 4;
    int ncol0 = wvu * 32;
    f32x4 acc0 = (f32x4){0.f, 0.f, 0.f, 0.f};
    f32x4 acc1 = (f32x4){0.f, 0.f, 0.f, 0.f};
    size_t b0off = (size_t)(ncol0 + l15) * 256;
    size_t b1off = (size_t)(ncol0 + 16 + l15) * 256;

    #pragma unroll
    for (int s = 0; s < 8; ++s) {
        int koff = s * 32 + q * 8;               // bf16 elements
        short8 b0 = *reinterpret_cast<const short8*>(Wt + b0off + koff);
        short8 b1 = *reinterpret_cast<const short8*>(Wt + b1off + koff);
        short8 a = *reinterpret_cast<const short8*>(Ab + swz(l15, koff * 2));
        // swapped operands: C col(lane&15)=out row, C row(q*4+reg)=out col
        acc0 = __builtin_amdgcn_mfma_f32_16x16x32_bf16(b0, a, acc0, 0, 0, 0);
        acc1 = __builtin_amdgcn_mfma_f32_16x16x32_bf16(b1, a, acc1, 0, 0, 0);
    }

    float4 bi0 = *reinterpret_cast<const float4*>(bias + ncol0 + q * 4);
    float4 bi1 = *reinterpret_cast<const float4*>(bias + ncol0 + 16 + q * 4);
    int row = blockRow + l15;                    // M % 16 == 0: always valid
    #pragma unroll
    for (int u = 0; u < 2; ++u) {
        int col = ncol0 + u * 16 + q * 4;
        f32x4 av = u ? acc1 : acc0;
        float4 bv = u ? bi1 : bi0;
        uint2 xu = *reinterpret_cast<const uint2*>(Ab + swz(l15, col * 2));
        float4 xb = upk(xu);
        float4 o;
        float h;
        h = av[0] + bv.x; o.x = xb.x + (h > 0.f ? h : SLOPE * h);
        h = av[1] + bv.y; o.y = xb.y + (h > 0.f ? h : SLOPE * h);
        h = av[2] + bv.z; o.z = xb.z + (h > 0.f ? h : SLOPE * h);
        h = av[3] + bv.w; o.w = xb.w + (h > 0.f ? h : SLOPE * h);
        *reinterpret_cast<float4*>(out + (size_t)row * 128 + col) = o;
    }
}

extern "C" void kernel_launch(void* const* d_in, const int* in_sizes, int n_in,
                              void* d_out, int out_size, void* d_ws, size_t ws_size,
                              hipStream_t stream) {
    const float* x_src = (const float*)d_in[0];
    const float* x_dst = (const float*)d_in[1];
    const int*   e     = (const int*)d_in[2];
    const float* W     = (const float*)d_in[3];
    const float* bias  = (const float*)d_in[4];
    float* out = (float*)d_out;

    int NS = in_sizes[0] / WIDTH;   // 100000 src nodes
    int E  = in_sizes[2] / 2;       // 800000
    int M  = in_sizes[1] / WIDTH;   // 100000 dst nodes
    int NB = (M + SBS - 1) / SBS;   // 196 (<= 256)

    // ws: xsb(mapped bf16)[NS*128] | Wt bf16[128*256] | counts[M] |
    //     offsets[M+1] | rank[E] | csr[E] | bsums[NB] | bbase[NB]   (~33 MB)
    unsigned short* xsb = (unsigned short*)d_ws;
    unsigned short* Wt  = xsb + (size_t)NS * WIDTH;
    unsigned* counts  = (unsigned*)(Wt + 128 * 256);
    int*      offsets = (int*)(counts + M);
    int*      rank    = offsets + (M + 1);
    int*      csr     = rank + E;
    unsigned* bsums   = (unsigned*)(csr + E);
    unsigned* bbase   = bsums + NB;
    size_t need = (char*)(bbase + NB) - (char*)d_ws;
    int use_xsb = (ws_size >= need) ? 1 : 0;
    if (!use_xsb) {   // fallback: no xsb; shift layout to skip it
        Wt = (unsigned short*)d_ws;
        counts  = (unsigned*)(Wt + 128 * 256);
        offsets = (int*)(counts + M);
        rank    = offsets + (M + 1);
        csr     = rank + E;
        bsums   = (unsigned*)(csr + E);
        bbase   = bsums + NB;
    }

    hipMemsetAsync(counts, 0, (size_t)M * sizeof(unsigned), stream);

    int nconv = use_xsb ? (NS * 32 + 255) / 256 : 0;
    int nhist = (E + 255) / 256;
    int nwt   = (128 * 64 + 255) / 256;
    prep_kernel<<<nconv + nhist + nwt, 256, 0, stream>>>(x_src, W, e, xsb, Wt,
                                                         counts, rank, NS, E,
                                                         nconv, nhist);
    block_sum_kernel<<<NB, SBS, 0, stream>>>(counts, bsums, M);
    bsum_scan_kernel<<<1, 256, 0, stream>>>(bsums, bbase, NB, offsets, M);
    scan_final_kernel<<<NB, SBS, 0, stream>>>(counts, bbase, offsets, M);
    scatter_kernel<<<(E + 255) / 256, 256, 0, stream>>>(e, offsets, rank, csr, E);

    int fblocks = (M + FBM - 1) / FBM;   // 6250
    if (use_xsb)
        fused_kernel<1><<<fblocks, 256, 0, stream>>>(x_src, xsb, x_dst, offsets,
                                                     csr, Wt, bias, out, M, E);
    else
        fused_kernel<0><<<fblocks, 256, 0, stream>>>(x_src, xsb, x_dst, offsets,
                                                     csr, Wt, bias, out, M, E);
}